// Round 3
// baseline (260.711 us; speedup 1.0000x reference)
//
#include <hip/hip_runtime.h>
#include <cstdint>

#define BB 2
#define CV 64
#define CR 20
#define EE 64
#define CO 64

// ---------------------------------------------------------------------------
// k_detect: decide whether index buffers are int32 (2 words per (.,2) entry)
// or int64 (4 words). int64 data has every odd 32-bit word == 0 (high words,
// indices < 2^31); int32 data has odd words = ind[:,:,1] = random in [0,Mv).
// P(all 4096 sampled odd words are 0 for int32 data) ~ 0.
// flag = words per (.,2) entry stride for the first field: 2 (i32) or 4 (i64).
// ---------------------------------------------------------------------------
__global__ __launch_bounds__(256) void k_detect(const int* __restrict__ r2p,
                                                int nchk, int* __restrict__ flag) {
  __shared__ int any;
  if (threadIdx.x == 0) any = 0;
  __syncthreads();
  int nz = 0;
  for (int i = threadIdx.x; i < nchk; i += 256) nz |= r2p[2 * i + 1];
  if (nz) atomicOr(&any, 1);
  __syncthreads();
  if (threadIdx.x == 0) *flag = (any == 0) ? 4 : 2;
}

// ---------------------------------------------------------------------------
// k_prep: G[cr][cv] = sum_e Wq[e][cr]*Wk[e][cv]   (20x64)
//         H[o][c]   = sum_e Wo[o][e]*Wv[e][c]     (64x64, o-major)
// blocks 0..4 -> G, blocks 5..20 -> H
// ---------------------------------------------------------------------------
__global__ __launch_bounds__(256) void k_prep(
    const float* __restrict__ Wq, const float* __restrict__ Wk,
    const float* __restrict__ Wv, const float* __restrict__ Wo,
    float* __restrict__ G, float* __restrict__ H) {
  int bid = blockIdx.x, t = threadIdx.x;
  if (bid < 5) {
    int idx = bid * 256 + t;
    if (idx < CR * CV) {
      int cr = idx / CV, cv = idx % CV;
      float s = 0.f;
      #pragma unroll
      for (int e = 0; e < EE; ++e) s += Wq[e * CR + cr] * Wk[e * CV + cv];
      G[idx] = s;
    }
  } else {
    int idx = (bid - 5) * 256 + t;  // 0..4095
    int o = idx >> 6, c = idx & 63;
    float s = 0.f;
    #pragma unroll
    for (int e = 0; e < EE; ++e) s += Wo[o * EE + e] * Wv[e * CV + c];
    H[idx] = s;
  }
}

// ---------------------------------------------------------------------------
// k_transpose_v: v_feat (B, 64, Mv) -> vt (B, Mv, 64). 64x64 LDS tiles.
// ---------------------------------------------------------------------------
__global__ __launch_bounds__(256) void k_transpose_v(
    const float* __restrict__ vf, float* __restrict__ vt, int Mv, int ntm) {
  __shared__ float tile[64][65];
  int b = blockIdx.x / ntm, tm = blockIdx.x % ntm;
  int m0 = tm * 64;
  int t = threadIdx.x;
  const float* src = vf + (size_t)b * CV * Mv;
  #pragma unroll
  for (int k = 0; k < 16; ++k) {
    int idx = t + k * 256;
    int c = idx >> 6, ml = idx & 63;          // consecutive t -> consecutive m: coalesced
    int m = m0 + ml;
    tile[c][ml] = (m < Mv) ? src[(size_t)c * Mv + m] : 0.f;
  }
  __syncthreads();
  float* dst = vt + (size_t)b * Mv * 64;
  #pragma unroll
  for (int k = 0; k < 16; ++k) {
    int idx = t + k * 256;
    int ml = idx >> 6, c = idx & 63;          // consecutive t -> consecutive c: coalesced
    int m = m0 + ml;
    if (m < Mv) dst[(size_t)m * 64 + c] = tile[c][ml];  // stride-65 LDS: conflict-free
  }
}

// ---------------------------------------------------------------------------
// k_gq: gq[b][j][cv] = sum_cr r_feat[b][cr][j] * G[cr][cv]   (B, Mr, 64)
// ---------------------------------------------------------------------------
__global__ __launch_bounds__(256) void k_gq(
    const float* __restrict__ rf, const float* __restrict__ G,
    float* __restrict__ gq, int Mr, int ntj) {
  __shared__ float Gl[CR * CV];   // [cr][cv]
  __shared__ float rt[CR][64];    // [cr][jl]
  int b = blockIdx.x / ntj, tj = blockIdx.x % ntj;
  int j0 = tj * 64;
  int t = threadIdx.x;
  for (int idx = t; idx < CR * CV; idx += 256) Gl[idx] = G[idx];
  const float* src = rf + (size_t)b * CR * Mr;
  for (int idx = t; idx < CR * 64; idx += 256) {
    int c = idx >> 6, jl = idx & 63;
    int j = j0 + jl;
    rt[c][jl] = (j < Mr) ? src[(size_t)c * Mr + j] : 0.f;
  }
  __syncthreads();
  int e = t & 63, w = t >> 6;
  float acc[16];
  #pragma unroll
  for (int i = 0; i < 16; ++i) acc[i] = 0.f;
  for (int c = 0; c < CR; ++c) {
    float g = Gl[c * 64 + e];       // 2-way bank alias: free
    #pragma unroll
    for (int i = 0; i < 16; ++i) acc[i] += g * rt[c][w * 16 + i];  // broadcast
  }
  float* dst = gq + ((size_t)b * Mr + j0) * 64;
  #pragma unroll
  for (int i = 0; i < 16; ++i) {
    int jl = w * 16 + i;
    if (j0 + jl < Mr) dst[(size_t)jl * 64 + e] = acc[i];
  }
}

// ---------------------------------------------------------------------------
// k_main: one wave per point p = (b, n). Zero LDS.
//  gather gq row, 4 raw v-columns from vt; 4 wave-reduced dots; softmax over
//  4; weighted raw-column sum ag; coalesced atomic scatter of ag into xs
//  (B, Mr, 64). The Wo*Wv projection is linear -> deferred to k_out_t.
// ---------------------------------------------------------------------------
__global__ __launch_bounds__(256) void k_main(
    const float* __restrict__ vt, const float* __restrict__ gq,
    const int* __restrict__ v2p, const int* __restrict__ r2p,
    float* __restrict__ xs, const int* __restrict__ flag,
    int Mv, int Mr, int N, int Nn, int P, int totWaves) {
  const int ws = *flag;           // 2 (i32 entries) or 4 (i64 entries); uniform
  int t = threadIdx.x;
  int lane = t & 63, w = t >> 6;
  int gw = blockIdx.x * 4 + w;
  for (int p = gw; p < P; p += totWaves) {
    int b = (p >= Nn) ? 1 : 0;      // BB == 2
    int n = p - b * Nn;
    int j = r2p[((size_t)b * Nn + n) * ws];
    float q = gq[((size_t)b * Mr + j) * 64 + lane];
    const int* vi = v2p + ((size_t)b * N + (size_t)n * 4) * ws;
    int i0 = vi[0 * ws], i1 = vi[1 * ws], i2 = vi[2 * ws], i3 = vi[3 * ws];
    const float* vb = vt + (size_t)b * Mv * 64;
    float c0 = vb[(size_t)i0 * 64 + lane];
    float c1 = vb[(size_t)i1 * 64 + lane];
    float c2 = vb[(size_t)i2 * 64 + lane];
    float c3 = vb[(size_t)i3 * 64 + lane];
    float s0 = q * c0, s1 = q * c1, s2 = q * c2, s3 = q * c3;
    #pragma unroll
    for (int off = 32; off > 0; off >>= 1) {
      s0 += __shfl_xor(s0, off);
      s1 += __shfl_xor(s1, off);
      s2 += __shfl_xor(s2, off);
      s3 += __shfl_xor(s3, off);
    }
    s0 *= 0.125f; s1 *= 0.125f; s2 *= 0.125f; s3 *= 0.125f;  // 1/sqrt(64)
    float mx = fmaxf(fmaxf(s0, s1), fmaxf(s2, s3));
    float e0 = __expf(s0 - mx), e1 = __expf(s1 - mx);
    float e2 = __expf(s2 - mx), e3 = __expf(s3 - mx);
    float inv = 1.f / (e0 + e1 + e2 + e3);
    e0 *= inv; e1 *= inv; e2 *= inv; e3 *= inv;
    float ag = e0 * c0 + e1 * c1 + e2 * c2 + e3 * c3;  // raw weighted column
    atomicAdd(&xs[((size_t)b * Mr + j) * 64 + lane], ag);  // 256B coalesced
  }
}

// ---------------------------------------------------------------------------
// k_out_t: out[b][o][j] = sum_c H[o][c] * xs[b][j][c]  (fused projection +
// transpose). 64 j's per block; thread = (jl = t&63, w = t>>6) computes 16 o's.
// ---------------------------------------------------------------------------
__global__ __launch_bounds__(256) void k_out_t(
    const float* __restrict__ xs, const float* __restrict__ H,
    float* __restrict__ out, int Mr, int ntj) {
  __shared__ float tile[64][65];
  __shared__ float Hl[CO * CV];   // [o][c]
  int b = blockIdx.x / ntj, tj = blockIdx.x % ntj;
  int j0 = tj * 64;
  int t = threadIdx.x;
  for (int idx = t; idx < CO * CV; idx += 256) Hl[idx] = H[idx];
  const float* src = xs + (size_t)b * Mr * 64;
  #pragma unroll
  for (int k = 0; k < 16; ++k) {
    int idx = t + k * 256;
    int jl = idx >> 6, c = idx & 63;          // coalesced read
    int j = j0 + jl;
    tile[jl][c] = (j < Mr) ? src[(size_t)j * 64 + c] : 0.f;
  }
  __syncthreads();
  int jl = t & 63, w = t >> 6;
  float acc[16];
  #pragma unroll
  for (int i = 0; i < 16; ++i) acc[i] = 0.f;
  for (int c = 0; c < 64; ++c) {
    float x = tile[jl][c];          // stride-65: conflict-free across lanes
    #pragma unroll
    for (int i = 0; i < 16; ++i) acc[i] += Hl[(w * 16 + i) * 64 + c] * x;  // uniform -> broadcast
  }
  int j = j0 + jl;
  if (j < Mr) {
    float* dst = out + (size_t)b * CO * Mr;
    #pragma unroll
    for (int i = 0; i < 16; ++i) dst[(size_t)(w * 16 + i) * Mr + j] = acc[i];  // coalesced
  }
}

// ---------------------------------------------------------------------------
extern "C" void kernel_launch(void* const* d_in, const int* in_sizes, int n_in,
                              void* d_out, int out_size, void* d_ws, size_t ws_size,
                              hipStream_t stream) {
  const float* v_feat = (const float*)d_in[0];
  const float* r_feat = (const float*)d_in[1];
  const float* Wq = (const float*)d_in[2];
  const float* Wk = (const float*)d_in[3];
  const float* Wv = (const float*)d_in[4];
  const float* Wo = (const float*)d_in[5];
  const int* v2p = (const int*)d_in[6];
  const int* r2p = (const int*)d_in[7];

  int Mv = in_sizes[0] / (BB * CV);   // 100000
  int Mr = in_sizes[1] / (BB * CR);   // 50000
  int N  = in_sizes[6] / (BB * 2);    // 262144
  int Nn = in_sizes[7] / (BB * 2);    // 65536  (bundle = 4)

  float* ws = (float*)d_ws;
  float* vt = ws;                                   // B*Mv*64   (51.2 MB)
  float* gq = vt + (size_t)BB * Mv * 64;            // B*Mr*64   (25.6 MB)
  float* xs = gq + (size_t)BB * Mr * 64;            // B*Mr*64   (25.6 MB)
  float* G  = xs + (size_t)BB * Mr * 64;            // 20*64
  float* H  = G + CR * CV;                          // 64*64
  int* flag = (int*)(H + CO * CV);
  float* out = (float*)d_out;

  hipMemsetAsync(xs, 0, (size_t)BB * Mr * 64 * sizeof(float), stream);

  k_detect<<<1, 256, 0, stream>>>(r2p, 4096, flag);

  k_prep<<<21, 256, 0, stream>>>(Wq, Wk, Wv, Wo, G, H);

  int ntm = (Mv + 63) / 64;
  k_transpose_v<<<BB * ntm, 256, 0, stream>>>(v_feat, vt, Mv, ntm);

  int ntj = (Mr + 63) / 64;
  k_gq<<<BB * ntj, 256, 0, stream>>>(r_feat, G, gq, Mr, ntj);

  int P = BB * Nn;
  int blocks = 2048;
  k_main<<<blocks, 256, 0, stream>>>(vt, gq, v2p, r2p, xs, flag,
                                     Mv, Mr, N, Nn, P, blocks * 4);

  k_out_t<<<BB * ntj, 256, 0, stream>>>(xs, H, out, Mr, ntj);
}

// Round 5
// 220.800 us; speedup vs baseline: 1.1808x; 1.1808x over previous
//
#include <hip/hip_runtime.h>
#include <cstdint>

#define BB 2
#define CV 64
#define CR 20
#define EE 64
#define CO 64

// ---------------------------------------------------------------------------
// k_prep: blocks 0..4  -> G[cr][cv] = sum_e Wq[e][cr]*Wk[e][cv]  (20x64)
//         blocks 5..20 -> H[o][c]   = sum_e Wo[o][e]*Wv[e][c]    (64x64)
//         block  21    -> index dtype detect (int32 vs int64)
// ---------------------------------------------------------------------------
__global__ __launch_bounds__(256) void k_prep(
    const float* __restrict__ Wq, const float* __restrict__ Wk,
    const float* __restrict__ Wv, const float* __restrict__ Wo,
    const int* __restrict__ r2p, float* __restrict__ G,
    float* __restrict__ H, int* __restrict__ flag) {
  int bid = blockIdx.x, t = threadIdx.x;
  if (bid < 5) {
    int idx = bid * 256 + t;
    if (idx < CR * CV) {
      int cr = idx / CV, cv = idx % CV;
      float s = 0.f;
      #pragma unroll
      for (int e = 0; e < EE; ++e) s += Wq[e * CR + cr] * Wk[e * CV + cv];
      G[idx] = s;
    }
  } else if (bid < 21) {
    int idx = (bid - 5) * 256 + t;  // 0..4095
    int o = idx >> 6, c = idx & 63;
    float s = 0.f;
    #pragma unroll
    for (int e = 0; e < EE; ++e) s += Wo[o * EE + e] * Wv[e * CV + c];
    H[idx] = s;
  } else {
    // int64 data: every odd 32-bit word is a zero high-word. int32 data:
    // odd words are ind[:,:,1] ~ U[0,Mv) -> P(all zero over 4096 words) ~ 0.
    __shared__ int any;
    if (t == 0) any = 0;
    __syncthreads();
    int nz = 0;
    for (int i = t; i < 4096; i += 256) nz |= r2p[2 * i + 1];
    if (nz) atomicOr(&any, 1);
    __syncthreads();
    if (t == 0) *flag = (any == 0) ? 4 : 2;  // words per (.,2) entry field
  }
}

// ---------------------------------------------------------------------------
// k_transpose_v: v_feat (B, 64, Mv) -> vt (B, Mv, 64). 64x64 tiles, float4
// global accesses both sides, scalar LDS with pad-65 (2-way max, free).
// ---------------------------------------------------------------------------
__global__ __launch_bounds__(256) void k_transpose_v(
    const float* __restrict__ vf, float* __restrict__ vt, int Mv, int ntm) {
  __shared__ float tile[64][65];
  int b = blockIdx.x / ntm, tm = blockIdx.x % ntm;
  int m0 = tm * 64;
  int t = threadIdx.x;
  const float* src = vf + (size_t)b * CV * Mv;
  bool fast = ((Mv & 3) == 0) && (m0 + 64 <= Mv);
  if (fast) {
    #pragma unroll
    for (int k = 0; k < 4; ++k) {
      int c = k * 16 + (t >> 4), l16 = t & 15;
      float4 v = *(const float4*)&src[(size_t)c * Mv + m0 + 4 * l16];
      tile[c][4 * l16 + 0] = v.x;
      tile[c][4 * l16 + 1] = v.y;
      tile[c][4 * l16 + 2] = v.z;
      tile[c][4 * l16 + 3] = v.w;
    }
  } else {
    #pragma unroll
    for (int k = 0; k < 16; ++k) {
      int idx = t + k * 256;
      int c = idx >> 6, ml = idx & 63;
      int m = m0 + ml;
      tile[c][ml] = (m < Mv) ? src[(size_t)c * Mv + m] : 0.f;
    }
  }
  __syncthreads();
  float* dst = vt + (size_t)b * Mv * 64;
  if (fast) {
    #pragma unroll
    for (int k = 0; k < 4; ++k) {
      int ml = k * 16 + (t >> 4), l16 = t & 15;
      float4 w;
      w.x = tile[4 * l16 + 0][ml];
      w.y = tile[4 * l16 + 1][ml];
      w.z = tile[4 * l16 + 2][ml];
      w.w = tile[4 * l16 + 3][ml];
      *(float4*)&dst[(size_t)(m0 + ml) * 64 + 4 * l16] = w;
    }
  } else {
    #pragma unroll
    for (int k = 0; k < 16; ++k) {
      int idx = t + k * 256;
      int ml = idx >> 6, c = idx & 63;
      int m = m0 + ml;
      if (m < Mv) dst[(size_t)m * 64 + c] = tile[c][ml];
    }
  }
}

// ---------------------------------------------------------------------------
// k_gq: gq[b][j][e] = sum_c r_feat[b][c][j] * G[c][e]   (B, Mr, 64)
// 4x4 register-blocked outer products; float4 LDS reads.
// ---------------------------------------------------------------------------
__global__ __launch_bounds__(256) void k_gq(
    const float* __restrict__ rf, const float* __restrict__ G,
    float* __restrict__ gq, int Mr, int ntj) {
  __shared__ float Gl[CR * 64];   // [c][e]
  __shared__ float rt[CR][68];    // [c][jl], pad 68: 16B-aligned rows
  int b = blockIdx.x / ntj, tj = blockIdx.x % ntj;
  int j0 = tj * 64;
  int t = threadIdx.x;
  for (int idx = t; idx < CR * 64; idx += 256) Gl[idx] = G[idx];
  const float* src = rf + (size_t)b * CR * Mr;
  for (int idx = t; idx < CR * 64; idx += 256) {
    int c = idx >> 6, jl = idx & 63;
    int j = j0 + jl;
    rt[c][jl] = (j < Mr) ? src[(size_t)c * Mr + j] : 0.f;
  }
  __syncthreads();
  int ti = t & 15, tjq = t >> 4;  // e-quad 4*ti, j-quad 4*tjq
  float acc[4][4];
  #pragma unroll
  for (int a = 0; a < 4; ++a)
    #pragma unroll
    for (int q = 0; q < 4; ++q) acc[a][q] = 0.f;
  for (int c = 0; c < CR; ++c) {
    float4 gx = *(const float4*)&Gl[c * 64 + 4 * ti];
    float4 xj = *(const float4*)&rt[c][4 * tjq];
    #pragma unroll
    for (int a = 0; a < 4; ++a) {
      float xv = (a == 0) ? xj.x : (a == 1) ? xj.y : (a == 2) ? xj.z : xj.w;
      acc[a][0] += xv * gx.x;
      acc[a][1] += xv * gx.y;
      acc[a][2] += xv * gx.z;
      acc[a][3] += xv * gx.w;
    }
  }
  #pragma unroll
  for (int a = 0; a < 4; ++a) {
    int j = j0 + 4 * tjq + a;
    if (j < Mr) {
      float4 w = make_float4(acc[a][0], acc[a][1], acc[a][2], acc[a][3]);
      *(float4*)&gq[((size_t)b * Mr + j) * 64 + 4 * ti] = w;
    }
  }
}

// ---------------------------------------------------------------------------
// k_main: one wave per 2 points; software-pipelined (next iteration's
// wave-uniform index loads issue while current gathers are in flight).
// WS = index word stride (2 for int32 entries, 4 for int64) — compile-time.
// ---------------------------------------------------------------------------
template <int WS>
__device__ __forceinline__ void main_loop(
    const float* __restrict__ vt, const float* __restrict__ gq,
    const int* __restrict__ v2p, const int* __restrict__ r2p,
    float* __restrict__ xs, int Mv, int Mr, int N, int Nn, int P,
    int gw, int totWaves) {
  int stride = totWaves * 2;
  int base = gw * 2;
  if (base >= P) return;
  // prologue: indices for the first iteration (wave-uniform -> s_loads)
  int b = (base >= Nn) ? 1 : 0;
  int n0 = base - b * Nn;
  int j0 = r2p[((size_t)b * Nn + n0) * WS];
  int j1 = r2p[((size_t)b * Nn + n0 + 1) * WS];
  const int* vi = v2p + ((size_t)b * N + (size_t)n0 * 4) * WS;
  int i00 = vi[0 * WS], i01 = vi[1 * WS], i02 = vi[2 * WS], i03 = vi[3 * WS];
  int i10 = vi[4 * WS], i11 = vi[5 * WS], i12 = vi[6 * WS], i13 = vi[7 * WS];
  int lane = threadIdx.x & 63;
  while (base < P) {
    const float* gqb = gq + (size_t)b * Mr * 64;
    const float* vb = vt + (size_t)b * Mv * 64;
    // issue current gathers
    float q0 = gqb[(size_t)j0 * 64 + lane];
    float q1 = gqb[(size_t)j1 * 64 + lane];
    float c00 = vb[(size_t)i00 * 64 + lane];
    float c01 = vb[(size_t)i01 * 64 + lane];
    float c02 = vb[(size_t)i02 * 64 + lane];
    float c03 = vb[(size_t)i03 * 64 + lane];
    float c10 = vb[(size_t)i10 * 64 + lane];
    float c11 = vb[(size_t)i11 * 64 + lane];
    float c12 = vb[(size_t)i12 * 64 + lane];
    float c13 = vb[(size_t)i13 * 64 + lane];
    size_t sj0 = ((size_t)b * Mr + j0) * 64 + lane;
    size_t sj1 = ((size_t)b * Mr + j1) * 64 + lane;
    // prefetch next iteration's indices (overlaps with gather latency)
    int nb = base + stride;
    int b2 = 0, pj0 = 0, pj1 = 0;
    int p00 = 0, p01 = 0, p02 = 0, p03 = 0, p10 = 0, p11 = 0, p12 = 0, p13 = 0;
    if (nb < P) {
      b2 = (nb >= Nn) ? 1 : 0;
      int n2 = nb - b2 * Nn;
      pj0 = r2p[((size_t)b2 * Nn + n2) * WS];
      pj1 = r2p[((size_t)b2 * Nn + n2 + 1) * WS];
      const int* vi2 = v2p + ((size_t)b2 * N + (size_t)n2 * 4) * WS;
      p00 = vi2[0 * WS]; p01 = vi2[1 * WS]; p02 = vi2[2 * WS]; p03 = vi2[3 * WS];
      p10 = vi2[4 * WS]; p11 = vi2[5 * WS]; p12 = vi2[6 * WS]; p13 = vi2[7 * WS];
    }
    // compute
    float s00 = q0 * c00, s01 = q0 * c01, s02 = q0 * c02, s03 = q0 * c03;
    float s10 = q1 * c10, s11 = q1 * c11, s12 = q1 * c12, s13 = q1 * c13;
    #pragma unroll
    for (int off = 32; off > 0; off >>= 1) {
      s00 += __shfl_xor(s00, off); s01 += __shfl_xor(s01, off);
      s02 += __shfl_xor(s02, off); s03 += __shfl_xor(s03, off);
      s10 += __shfl_xor(s10, off); s11 += __shfl_xor(s11, off);
      s12 += __shfl_xor(s12, off); s13 += __shfl_xor(s13, off);
    }
    {
      float a = s00 * 0.125f, b3 = s01 * 0.125f, c3 = s02 * 0.125f, d = s03 * 0.125f;
      float mx = fmaxf(fmaxf(a, b3), fmaxf(c3, d));
      float e0 = __expf(a - mx), e1 = __expf(b3 - mx);
      float e2 = __expf(c3 - mx), e3 = __expf(d - mx);
      float inv = 1.f / (e0 + e1 + e2 + e3);
      float ag = (e0 * c00 + e1 * c01 + e2 * c02 + e3 * c03) * inv;
      atomicAdd(&xs[sj0], ag);
    }
    {
      float a = s10 * 0.125f, b3 = s11 * 0.125f, c3 = s12 * 0.125f, d = s13 * 0.125f;
      float mx = fmaxf(fmaxf(a, b3), fmaxf(c3, d));
      float e0 = __expf(a - mx), e1 = __expf(b3 - mx);
      float e2 = __expf(c3 - mx), e3 = __expf(d - mx);
      float inv = 1.f / (e0 + e1 + e2 + e3);
      float ag = (e0 * c10 + e1 * c11 + e2 * c12 + e3 * c13) * inv;
      atomicAdd(&xs[sj1], ag);
    }
    // rotate pipeline
    base = nb; b = b2; j0 = pj0; j1 = pj1;
    i00 = p00; i01 = p01; i02 = p02; i03 = p03;
    i10 = p10; i11 = p11; i12 = p12; i13 = p13;
  }
}

__global__ __launch_bounds__(256) void k_main(
    const float* __restrict__ vt, const float* __restrict__ gq,
    const int* __restrict__ v2p, const int* __restrict__ r2p,
    float* __restrict__ xs, const int* __restrict__ flag,
    int Mv, int Mr, int N, int Nn, int P, int totWaves) {
  int t = threadIdx.x;
  int gw = blockIdx.x * 4 + (t >> 6);
  if (*flag == 2)
    main_loop<2>(vt, gq, v2p, r2p, xs, Mv, Mr, N, Nn, P, gw, totWaves);
  else
    main_loop<4>(vt, gq, v2p, r2p, xs, Mv, Mr, N, Nn, P, gw, totWaves);
}

// ---------------------------------------------------------------------------
// k_out_t: out[b][o][j] = sum_c H[o][c] * xs[b][j][c]. 64x64 tile GEMM,
// 4x4 register blocking, float4 LDS reads, XOR-swizzled H tile, LDS-staged
// float4 coalesced stores.
// ---------------------------------------------------------------------------
__device__ __forceinline__ int hsw(int fidx) {  // swizzle col-quad by row>>2
  return fidx ^ (((fidx >> 8) & 7) << 2);
}

__global__ __launch_bounds__(256) void k_out_t(
    const float* __restrict__ xs, const float* __restrict__ H,
    float* __restrict__ out, int Mr, int ntj) {
  __shared__ float Hl[CO * CV];   // [o][c], XOR-swizzled quads
  __shared__ float xt[64][68];    // [j][c] then reused as [o][jl]
  int b = blockIdx.x / ntj, tj = blockIdx.x % ntj;
  int j0 = tj * 64;
  int t = threadIdx.x;
  for (int idx = t; idx < CO * CV; idx += 256) Hl[hsw(idx)] = H[idx];
  const float* src = xs + (size_t)b * Mr * 64;
  #pragma unroll
  for (int k = 0; k < 4; ++k) {
    int jl = k * 16 + (t >> 4), c4 = t & 15;
    int j = j0 + jl;
    float4 v = (j < Mr) ? *(const float4*)&src[(size_t)j * 64 + 4 * c4]
                        : make_float4(0.f, 0.f, 0.f, 0.f);
    *(float4*)&xt[jl][4 * c4] = v;
  }
  __syncthreads();
  int ti = t & 15;                 // o-quad 4*ti
  int tjq4 = t >> 4;               // j-quad 4*tjq4 (0..15)
  float acc[4][4];
  #pragma unroll
  for (int a = 0; a < 4; ++a)
    #pragma unroll
    for (int q = 0; q < 4; ++q) acc[a][q] = 0.f;
  #pragma unroll 4
  for (int cq = 0; cq < 16; ++cq) {
    float4 xv[4], hb[4];
    #pragma unroll
    for (int a = 0; a < 4; ++a)
      xv[a] = *(const float4*)&xt[4 * tjq4 + a][4 * cq];
    #pragma unroll
    for (int q = 0; q < 4; ++q) {
      int row = 4 * ti + q;
      hb[q] = *(const float4*)&Hl[hsw(row * 64 + 4 * cq)];
    }
    #pragma unroll
    for (int a = 0; a < 4; ++a)
      #pragma unroll
      for (int q = 0; q < 4; ++q)
        acc[a][q] += xv[a].x * hb[q].x + xv[a].y * hb[q].y +
                     xv[a].z * hb[q].z + xv[a].w * hb[q].w;
  }
  __syncthreads();
  // stage transposed result: xt[o][jl]
  #pragma unroll
  for (int a = 0; a < 4; ++a)
    #pragma unroll
    for (int q = 0; q < 4; ++q)
      xt[4 * ti + q][4 * tjq4 + a] = acc[a][q];
  __syncthreads();
  float* dst = out + (size_t)b * CO * Mr;
  #pragma unroll
  for (int k = 0; k < 4; ++k) {
    int o = k * 16 + (t >> 4), j4 = t & 15;
    int j = j0 + 4 * j4;
    if (j + 3 < Mr) {
      *(float4*)&dst[(size_t)o * Mr + j] = *(const float4*)&xt[o][4 * j4];
    } else {
      #pragma unroll
      for (int i = 0; i < 4; ++i)
        if (j + i < Mr) dst[(size_t)o * Mr + j + i] = xt[o][4 * j4 + i];
    }
  }
}

// ---------------------------------------------------------------------------
extern "C" void kernel_launch(void* const* d_in, const int* in_sizes, int n_in,
                              void* d_out, int out_size, void* d_ws, size_t ws_size,
                              hipStream_t stream) {
  const float* v_feat = (const float*)d_in[0];
  const float* r_feat = (const float*)d_in[1];
  const float* Wq = (const float*)d_in[2];
  const float* Wk = (const float*)d_in[3];
  const float* Wv = (const float*)d_in[4];
  const float* Wo = (const float*)d_in[5];
  const int* v2p = (const int*)d_in[6];
  const int* r2p = (const int*)d_in[7];

  int Mv = in_sizes[0] / (BB * CV);   // 100000
  int Mr = in_sizes[1] / (BB * CR);   // 50000
  int N  = in_sizes[6] / (BB * 2);    // 262144
  int Nn = in_sizes[7] / (BB * 2);    // 65536  (bundle = 4)

  float* ws = (float*)d_ws;
  float* vt = ws;                                   // B*Mv*64   (51.2 MB)
  float* gq = vt + (size_t)BB * Mv * 64;            // B*Mr*64   (25.6 MB)
  float* xs = gq + (size_t)BB * Mr * 64;            // B*Mr*64   (25.6 MB)
  float* G  = xs + (size_t)BB * Mr * 64;            // 20*64
  float* H  = G + CR * CV;                          // 64*64
  int* flag = (int*)(H + CO * CV);
  float* out = (float*)d_out;

  hipMemsetAsync(xs, 0, (size_t)BB * Mr * 64 * sizeof(float), stream);

  k_prep<<<22, 256, 0, stream>>>(Wq, Wk, Wv, Wo, r2p, G, H, flag);

  int ntm = (Mv + 63) / 64;
  k_transpose_v<<<BB * ntm, 256, 0, stream>>>(v_feat, vt, Mv, ntm);

  int ntj = (Mr + 63) / 64;
  k_gq<<<BB * ntj, 256, 0, stream>>>(r_feat, G, gq, Mr, ntj);

  int P = BB * Nn;
  int blocks = 2048;
  k_main<<<blocks, 256, 0, stream>>>(vt, gq, v2p, r2p, xs, flag,
                                     Mv, Mr, N, Nn, P, blocks * 4);

  k_out_t<<<BB * ntj, 256, 0, stream>>>(xs, H, out, Mr, ntj);
}